// Round 3
// baseline (325.324 us; speedup 1.0000x reference)
//
#include <hip/hip_runtime.h>

// Problem geometry (fixed by setup_inputs): im[16, 3, 1024, 1024] float32.
#define HW   1048576          // 1024*1024 elements per plane
#define HWQ  262144           // float4-groups per plane (HW/4)
#define NT   4194304          // total threads = 16 images * HWQ

// D65 white point (u'n, v'n) — computed in double exactly as the reference does.
#define DEN65 (-2.0 * 0.31271 + 12.0 * 0.32902 + 3.0)
#define UN_F  ((float)(4.0 * 0.31271 / DEN65))
#define VN_F  ((float)(9.0 * 0.32902 / DEN65))

static __device__ __forceinline__ float fpow(float x, float p) {
    // 2^(p * log2 x) via hardware v_log_f32 / v_exp_f32 (~1 ULP each)
    return __builtin_amdgcn_exp2f(p * __builtin_amdgcn_logf(x));
}

// jnp.nan_to_num(x, nan=0.0): NaN->0, +inf->FLT_MAX, -inf->-FLT_MAX
static __device__ __forceinline__ float nan0(float x) {
    if (x != x) return 0.0f;
    return fminf(fmaxf(x, -3.4028234663852886e38f), 3.4028234663852886e38f);
}

static __device__ __forceinline__ float srgb2lin(float x) {
    float lo = x * (float)(1.0 / 12.92);
    float hi = fpow((x + 0.055f) * (float)(1.0 / 1.055), 2.4f);
    return (x <= 0.04045f) ? lo : hi;
}

static __device__ __forceinline__ float lin2srgb(float x) {
    x = fminf(fmaxf(x, 0.0f), 1.0f);
    float lo = x * 12.92f;
    float hi = fmaf(1.055f, fpow(x, (float)(1.0 / 2.4)), -0.055f);
    return (x <= 0.0031308f) ? lo : hi;
}

static __device__ __forceinline__ void px(float r, float g, float b,
                                          float &ro, float &go, float &bo) {
    // ---- sRGB -> linear ----
    float lr = srgb2lin(r);
    float lg = srgb2lin(g);
    float lb = srgb2lin(b);

    // ---- linear RGB -> XYZ (Rec.709), scaled x100 ----
    float X = 100.0f * fmaf(0.1804375f, lb, fmaf(0.3575761f, lg, 0.4124564f * lr));
    float Y = 100.0f * fmaf(0.0721750f, lb, fmaf(0.7151522f, lg, 0.2126728f * lr));
    float Z = 100.0f * fmaf(0.9503041f, lb, fmaf(0.1191920f, lg, 0.0193339f * lr));

    // ---- XYZ -> LUV ----
    float den  = fmaf(3.0f, Z, fmaf(15.0f, Y, X));
    float rden = __builtin_amdgcn_rcpf(den);          // den==0 -> inf -> NaN chain, matches ref
    float u_p  = (4.0f * X) * rden;
    float v_p  = (9.0f * Y) * rden;
    float t    = Y * 0.01f;

    float Llo = 903.2962962962963f * t;               // (29/3)^3 * t
    float Lhi = fmaf(116.0f, fpow(t, (float)(1.0 / 3.0)), -16.0f);
    float L   = (t <= 0.008856451679035631f) ? Llo : Lhi;   // (6/29)^3

    float t13L = 13.0f * L;
    float u_s  = fmaf(t13L, u_p - UN_F, 5.0f);        // + DELTA_U
    float v_s  = fmaf(t13L, v_p - VN_F, -5.0f);       // + DELTA_V

    // ---- LUV -> XYZ ----
    float r13  = __builtin_amdgcn_rcpf(t13L);
    float u_p2 = fmaf(u_s, r13, UN_F);
    float v_p2 = fmaf(v_s, r13, VN_F);

    float Y2lo = (100.0f * L) * 0.0011070564598794539f;  // 100*L*(3/29)^3
    float c    = (L + 16.0f) * (float)(1.0 / 116.0);
    float Y2hi = 100.0f * ((c * c) * c);
    float Y2   = (L <= 8.0f) ? Y2lo : Y2hi;

    float r4v = __builtin_amdgcn_rcpf(4.0f * v_p2);
    float X2  = nan0(((Y2 * 9.0f) * u_p2) * r4v);
    float Z2  = nan0((Y2 * ((12.0f - 3.0f * u_p2) - 20.0f * v_p2)) * r4v);

    float xn = X2 * 0.01f;
    float yn = Y2 * 0.01f;
    float zn = Z2 * 0.01f;

    // ---- XYZ -> linear RGB (inverse matrix, standard sRGB D65) ----
    float lr2 = fmaf(-0.49853140955601605f, zn, fmaf(-1.5371385127977166f, yn,  3.2404541621141045f * xn));
    float lg2 = fmaf( 0.041556017530349834f, zn, fmaf( 1.8760108454466942f, yn, -0.96926603050518f  * xn));
    float lb2 = fmaf( 1.0572251882231791f,  zn, fmaf(-0.20402591351675387f, yn,  0.05564343095911469f * xn));

    // ---- linear -> sRGB ----
    ro = lin2srgb(lr2);
    go = lin2srgb(lg2);
    bo = lin2srgb(lb2);
}

__global__ __launch_bounds__(256) void chroma_shift_kernel(const float* __restrict__ im,
                                                           float* __restrict__ out) {
    int tid = blockIdx.x * 256 + threadIdx.x;
    if (tid >= NT) return;
    int n = tid >> 18;            // image index (HWQ = 2^18 float4-groups per plane)
    int q = tid & (HWQ - 1);      // float4-group within plane
    int base = n * (3 * HWQ) + q;

    const float4* in4 = (const float4*)im;
    float4*       o4  = (float4*)out;

    float4 R = in4[base];
    float4 G = in4[base + HWQ];
    float4 B = in4[base + 2 * HWQ];

    float4 Ro, Go, Bo;
    px(R.x, G.x, B.x, Ro.x, Go.x, Bo.x);
    px(R.y, G.y, B.y, Ro.y, Go.y, Bo.y);
    px(R.z, G.z, B.z, Ro.z, Go.z, Bo.z);
    px(R.w, G.w, B.w, Ro.w, Go.w, Bo.w);

    o4[base]           = Ro;
    o4[base + HWQ]     = Go;
    o4[base + 2 * HWQ] = Bo;
}

extern "C" void kernel_launch(void* const* d_in, const int* in_sizes, int n_in,
                              void* d_out, int out_size, void* d_ws, size_t ws_size,
                              hipStream_t stream) {
    const float* im  = (const float*)d_in[0];
    float*       out = (float*)d_out;
    // 4,194,304 threads, each handles 4 pixels (x3 channels) -> 16384 blocks of 256
    chroma_shift_kernel<<<dim3(NT / 256), dim3(256), 0, stream>>>(im, out);
}

// Round 6
// 315.866 us; speedup vs baseline: 1.0299x; 1.0299x over previous
//
#include <hip/hip_runtime.h>

// Problem geometry (fixed by setup_inputs): im[16, 3, 1024, 1024] float32.
#define HW   1048576          // 1024*1024 elements per plane
#define HWQ  262144           // float4-groups per plane (HW/4)
#define NT   4194304          // total threads = 16 images * HWQ

// Native 4-float vector (NOT HIP_vector_type) so nontemporal builtins accept it.
typedef float f32x4 __attribute__((ext_vector_type(4)));

static __device__ __forceinline__ float fpow(float x, float p) {
    // 2^(p * log2 x) via hardware v_log_f32 / v_exp_f32 (~1 ULP each)
    return __builtin_amdgcn_exp2f(p * __builtin_amdgcn_logf(x));
}

// jnp.nan_to_num(x, nan=0.0): NaN->0, +inf->FLT_MAX, -inf->-FLT_MAX
static __device__ __forceinline__ float nan0(float x) {
    if (x != x) return 0.0f;
    return fminf(fmaxf(x, -3.4028234663852886e38f), 3.4028234663852886e38f);
}

static __device__ __forceinline__ float srgb2lin(float x) {
    float lo = x * (float)(1.0 / 12.92);
    float hi = fpow((x + 0.055f) * (float)(1.0 / 1.055), 2.4f);
    return (x <= 0.04045f) ? lo : hi;
}

static __device__ __forceinline__ float lin2srgb(float x) {
    x = fminf(fmaxf(x, 0.0f), 1.0f);
    float lo = x * 12.92f;
    float hi = fmaf(1.055f, fpow(x, (float)(1.0 / 2.4)), -0.055f);
    return (x <= 0.0031308f) ? lo : hi;
}

static __device__ __forceinline__ void px(float r, float g, float b,
                                          float &ro, float &go, float &bo) {
    // ---- sRGB -> linear ----
    float lr = srgb2lin(r);
    float lg = srgb2lin(g);
    float lb = srgb2lin(b);

    // ---- linear RGB -> XYZ (Rec.709), scaled x100 ----
    float X = 100.0f * fmaf(0.1804375f, lb, fmaf(0.3575761f, lg, 0.4124564f * lr));
    float Y = 100.0f * fmaf(0.0721750f, lb, fmaf(0.7151522f, lg, 0.2126728f * lr));
    float Z = 100.0f * fmaf(0.9503041f, lb, fmaf(0.1191920f, lg, 0.0193339f * lr));

    // ---- XYZ -> u'v' + L ----
    float den  = fmaf(3.0f, Z, fmaf(15.0f, Y, X));
    float rden = __builtin_amdgcn_rcpf(den);          // den==0 -> inf -> NaN chain, matches ref
    float u_p  = (4.0f * X) * rden;                   // 0*inf -> NaN for black pixels (as ref)
    float v_p  = (9.0f * Y) * rden;
    float t    = Y * 0.01f;

    float Llo = 903.2962962962963f * t;               // (29/3)^3 * t
    float Lhi = fmaf(116.0f, fpow(t, (float)(1.0 / 3.0)), -16.0f);
    float L   = (t <= 0.008856451679035631f) ? Llo : Lhi;   // (6/29)^3

    // ---- chroma shift collapsed algebraically ----
    // ref: u_s = 13L(u_p-un)+5 ; u_p2 = u_s/(13L)+un  ==> u_p2 = u_p + 5/(13L)
    //      v_s = 13L(v_p-vn)-5 ; v_p2 = v_s/(13L)+vn  ==> v_p2 = v_p - 5/(13L)
    // ref: Y2 == Y identically (both branches invert exactly; thresholds coincide:
    //      L<=8 <=> t<=(6/29)^3 since Llo(thresh)=8 and Lhi is monotone).
    float s    = 5.0f * __builtin_amdgcn_rcpf(13.0f * L);   // L==0 -> inf -> NaN chain as ref
    float u_p2 = u_p + s;
    float v_p2 = v_p - s;
    float Y2   = Y;

    float r4v = __builtin_amdgcn_rcpf(4.0f * v_p2);
    float X2  = nan0(((Y2 * 9.0f) * u_p2) * r4v);
    float Z2  = nan0((Y2 * ((12.0f - 3.0f * u_p2) - 20.0f * v_p2)) * r4v);

    float xn = X2 * 0.01f;
    float yn = Y2 * 0.01f;
    float zn = Z2 * 0.01f;

    // ---- XYZ -> linear RGB (inverse matrix, standard sRGB D65) ----
    float lr2 = fmaf(-0.49853140955601605f, zn, fmaf(-1.5371385127977166f, yn,  3.2404541621141045f * xn));
    float lg2 = fmaf( 0.041556017530349834f, zn, fmaf( 1.8760108454466942f, yn, -0.96926603050518f  * xn));
    float lb2 = fmaf( 1.0572251882231791f,  zn, fmaf(-0.20402591351675387f, yn,  0.05564343095911469f * xn));

    // ---- linear -> sRGB ----
    ro = lin2srgb(lr2);
    go = lin2srgb(lg2);
    bo = lin2srgb(lb2);
}

__global__ __launch_bounds__(256) void chroma_shift_kernel(const float* __restrict__ im,
                                                           float* __restrict__ out) {
    int tid = blockIdx.x * 256 + threadIdx.x;
    if (tid >= NT) return;
    int n = tid >> 18;            // image index (HWQ = 2^18 float4-groups per plane)
    int q = tid & (HWQ - 1);      // float4-group within plane
    int base = n * (3 * HWQ) + q;

    const f32x4* in4 = (const f32x4*)im;
    f32x4*       o4  = (f32x4*)out;

    // Pure streaming data (no reuse): nontemporal to keep L2/LLC clean.
    f32x4 R = __builtin_nontemporal_load(&in4[base]);
    f32x4 G = __builtin_nontemporal_load(&in4[base + HWQ]);
    f32x4 B = __builtin_nontemporal_load(&in4[base + 2 * HWQ]);

    f32x4 Ro, Go, Bo;
    // ext_vector lanes aren't lvalue-bindable to float& -> use scalar temporaries.
    {
        float a, c, d;
        px(R.x, G.x, B.x, a, c, d); Ro.x = a; Go.x = c; Bo.x = d;
        px(R.y, G.y, B.y, a, c, d); Ro.y = a; Go.y = c; Bo.y = d;
        px(R.z, G.z, B.z, a, c, d); Ro.z = a; Go.z = c; Bo.z = d;
        px(R.w, G.w, B.w, a, c, d); Ro.w = a; Go.w = c; Bo.w = d;
    }

    __builtin_nontemporal_store(Ro, &o4[base]);
    __builtin_nontemporal_store(Go, &o4[base + HWQ]);
    __builtin_nontemporal_store(Bo, &o4[base + 2 * HWQ]);
}

extern "C" void kernel_launch(void* const* d_in, const int* in_sizes, int n_in,
                              void* d_out, int out_size, void* d_ws, size_t ws_size,
                              hipStream_t stream) {
    const float* im  = (const float*)d_in[0];
    float*       out = (float*)d_out;
    // 4,194,304 threads, each handles 4 pixels (x3 channels) -> 16384 blocks of 256
    chroma_shift_kernel<<<dim3(NT / 256), dim3(256), 0, stream>>>(im, out);
}